// Round 1
// baseline (127.003 us; speedup 1.0000x reference)
//
#include <hip/hip_runtime.h>
#include <hip/hip_bf16.h>
#include <stdint.h>

#define U_ROWS 4096
#define P_DIM  1024
#define TILE   128
#define BK     32

typedef __bf16 bf16x8 __attribute__((ext_vector_type(8)));
typedef float  f32x4  __attribute__((ext_vector_type(4)));

__device__ __forceinline__ unsigned short f2bf_rne(float f) {
    unsigned int u = __float_as_uint(f);
    u += 0x7fffu + ((u >> 16) & 1u);          // round-to-nearest-even
    return (unsigned short)(u >> 16);
}

// One block per row: L2-normalize (eps-clamped) and emit bf16.
__global__ __launch_bounds__(256) void normalize_rows_kernel(
    const float* __restrict__ in1, const float* __restrict__ in2,
    unsigned short* __restrict__ out, float* __restrict__ loss_out) {
    const int row = blockIdx.x;
    const float* src = (row < U_ROWS) ? (in1 + (size_t)row * P_DIM)
                                      : (in2 + (size_t)(row - U_ROWS) * P_DIM);
    const int tid = threadIdx.x;
    float4 v = ((const float4*)src)[tid];     // 256 threads x 4 floats = 1024
    float ss = v.x * v.x + v.y * v.y + v.z * v.z + v.w * v.w;
    #pragma unroll
    for (int off = 32; off > 0; off >>= 1) ss += __shfl_down(ss, off, 64);
    __shared__ float red[4];
    const int w = tid >> 6, lane = tid & 63;
    if (lane == 0) red[w] = ss;
    __syncthreads();
    const float total = red[0] + red[1] + red[2] + red[3];
    const float scale = 1.0f / fmaxf(sqrtf(total), 1e-8f);
    ushort4 o;
    o.x = f2bf_rne(v.x * scale);
    o.y = f2bf_rne(v.y * scale);
    o.z = f2bf_rne(v.z * scale);
    o.w = f2bf_rne(v.w * scale);
    ((ushort4*)(out + (size_t)row * P_DIM))[tid] = o;
    if (row == 0 && tid == 0) *loss_out = 0.0f;   // zero-init accumulator
}

// C = N1 * N2^T fused with sum((1-c)^2). 128x128 tile / block, 4 waves,
// each wave does 4x4 tiles of 16x16x32 bf16 MFMA. Staging via
// global_load_lds width=16 (wave-uniform base + lane*16 -> contiguous
// [16 rows][32 cols] chunks, no padding).
__global__ __launch_bounds__(256) void cosloss_gemm_kernel(
    const unsigned short* __restrict__ n1, const unsigned short* __restrict__ n2,
    float* __restrict__ loss_out) {
    __shared__ unsigned short As[TILE * BK];   // 8 KB
    __shared__ unsigned short Bs[TILE * BK];   // 8 KB
    __shared__ float red[4];

    const int tid  = threadIdx.x;
    const int w    = tid >> 6;
    const int lane = tid & 63;
    const int rb = blockIdx.y, cb = blockIdx.x;

    const unsigned short* gA = n1 + (size_t)rb * TILE * P_DIM;
    const unsigned short* gB = n2 + (size_t)cb * TILE * P_DIM;

    // waves 0,1 stage A (issues 0..3 / 4..7); waves 2,3 stage B
    const unsigned short* gbase = (w < 2) ? gA : gB;
    unsigned short* sbase = (w < 2) ? As : Bs;
    const int wj   = (w & 1) * 4;          // first 1KB-issue index for this wave
    const int srow = lane >> 2;            // row within a 16-row issue
    const int scol = (lane & 3) * 8;       // bf16-element col offset

    f32x4 acc[4][4];
    #pragma unroll
    for (int i = 0; i < 4; ++i)
        #pragma unroll
        for (int j = 0; j < 4; ++j)
            acc[i][j] = (f32x4){0.f, 0.f, 0.f, 0.f};

    const int wr = (w >> 1) * 64;          // wave's row origin in tile
    const int wc = (w & 1) * 64;           // wave's col origin in tile
    const int fr = lane & 15;              // fragment m/n index
    const int fk = (lane >> 4) * 8;        // fragment k offset (quad*8)

    for (int kt = 0; kt < P_DIM / BK; ++kt) {
        #pragma unroll
        for (int jj = 0; jj < 4; ++jj) {
            const int j = wj + jj;
            const unsigned short* g =
                gbase + (size_t)(j * 16 + srow) * P_DIM + kt * BK + scol;
            __builtin_amdgcn_global_load_lds(
                (const __attribute__((address_space(1))) void*)g,
                (__attribute__((address_space(3))) void*)(sbase + j * 512),
                16, 0, 0);
        }
        __syncthreads();   // drains vmcnt(0): LDS tiles ready

        bf16x8 af[4], bfr[4];
        #pragma unroll
        for (int i = 0; i < 4; ++i) {
            af[i]  = *(const bf16x8*)(&As[(wr + i * 16 + fr) * BK + fk]);
            bfr[i] = *(const bf16x8*)(&Bs[(wc + i * 16 + fr) * BK + fk]);
        }
        #pragma unroll
        for (int mi = 0; mi < 4; ++mi)
            #pragma unroll
            for (int ni = 0; ni < 4; ++ni)
                acc[mi][ni] = __builtin_amdgcn_mfma_f32_16x16x32_bf16(
                    af[mi], bfr[ni], acc[mi][ni], 0, 0, 0);
        __syncthreads();   // all waves done reading LDS before next stage
    }

    // Epilogue: sum (1-c)^2 over this block's 128x128 tile.
    // C/D lane mapping is irrelevant for a full-tile sum.
    float local = 0.0f;
    #pragma unroll
    for (int mi = 0; mi < 4; ++mi)
        #pragma unroll
        for (int ni = 0; ni < 4; ++ni)
            #pragma unroll
            for (int r = 0; r < 4; ++r) {
                const float d = 1.0f - acc[mi][ni][r];
                local += d * d;
            }
    #pragma unroll
    for (int off = 32; off > 0; off >>= 1) local += __shfl_down(local, off, 64);
    if (lane == 0) red[w] = local;
    __syncthreads();
    if (tid == 0) atomicAdd(loss_out, red[0] + red[1] + red[2] + red[3]);
}

extern "C" void kernel_launch(void* const* d_in, const int* in_sizes, int n_in,
                              void* d_out, int out_size, void* d_ws, size_t ws_size,
                              hipStream_t stream) {
    const float* in1 = (const float*)d_in[0];
    const float* in2 = (const float*)d_in[1];
    float* out = (float*)d_out;
    unsigned short* nrm = (unsigned short*)d_ws;   // 8192x1024 bf16 = 16 MB

    normalize_rows_kernel<<<U_ROWS * 2, 256, 0, stream>>>(in1, in2, nrm, out);

    dim3 grid(U_ROWS / TILE, U_ROWS / TILE);       // 32 x 32 = 1024 blocks
    cosloss_gemm_kernel<<<grid, 256, 0, stream>>>(
        nrm, nrm + (size_t)U_ROWS * P_DIM, out);
}

// Round 2
// 104.205 us; speedup vs baseline: 1.2188x; 1.2188x over previous
//
#include <hip/hip_runtime.h>
#include <hip/hip_bf16.h>
#include <stdint.h>

#define U_ROWS 4096
#define P_DIM  1024
#define TILE   128
#define BK     64      // fp8 bytes per k-tile

typedef float f32x4 __attribute__((ext_vector_type(4)));
typedef long  lx2   __attribute__((ext_vector_type(2)));

// Row L2-normalize (eps-clamped), scale by 16, emit OCP fp8 e4m3 in a
// k-permuted layout: within each 64-col block, global k lives at
// pos = (k&7) + ((k>>3)&3)*16 + ((k>>5)&1)*8, so that a ds_read_b128 at
// byte q*16 yields k=q*8..q*8+7 (bytes 0-7) and k=32+q*8.. (bytes 8-15) --
// exactly the two 16x16x32 fp8 MFMA fragments for quad q.
__global__ __launch_bounds__(256) void norm_fp8_kernel(
    const float* __restrict__ in1, const float* __restrict__ in2,
    uint8_t* __restrict__ out, float* __restrict__ loss_out) {
    const int w = threadIdx.x >> 6, lane = threadIdx.x & 63;
    const int row = blockIdx.x * 4 + w;
    const float* src = (row < U_ROWS) ? (in1 + (size_t)row * P_DIM)
                                      : (in2 + (size_t)(row - U_ROWS) * P_DIM);
    float4 v[4];
    float ss = 0.0f;
    #pragma unroll
    for (int j = 0; j < 4; ++j) {
        v[j] = ((const float4*)src)[j * 64 + lane];   // coalesced 16B/lane
        ss += v[j].x * v[j].x + v[j].y * v[j].y + v[j].z * v[j].z + v[j].w * v[j].w;
    }
    #pragma unroll
    for (int off = 32; off > 0; off >>= 1) ss += __shfl_xor(ss, off, 64);
    const float inv = 16.0f / fmaxf(sqrtf(ss), 1e-8f);

    uint8_t* orow = out + (size_t)row * P_DIM;
    #pragma unroll
    for (int j = 0; j < 4; ++j) {
        int c = j * 256 + lane * 4;                   // source col (mult of 4)
        int pos = (c & 4) + (((c >> 3) & 3) * 16) + (((c >> 5) & 1) * 8);
        int newc = (c & ~63) | pos;
        int d = __builtin_amdgcn_cvt_pk_fp8_f32(v[j].x * inv, v[j].y * inv, 0, false);
        d = __builtin_amdgcn_cvt_pk_fp8_f32(v[j].z * inv, v[j].w * inv, d, true);
        *(int*)(orow + newc) = d;
    }
    if (blockIdx.x == 0 && threadIdx.x == 0) *loss_out = 0.0f;
}

// C = N1*N2^T fused with sum((1-c)^2), fp8 e4m3 inputs scaled by 16
// (acc = 256*cos). 128x128 tile, BK=64, 4 waves x (4x4) 16x16x32 fp8 MFMA,
// two k-steps per iter. global_load_lds width=16 staging; XCD-striped cb.
__global__ __launch_bounds__(256) void cosloss_gemm_fp8(
    const uint8_t* __restrict__ n1, const uint8_t* __restrict__ n2,
    float* __restrict__ loss_out) {
    __shared__ uint8_t As[TILE * BK];   // 8 KB
    __shared__ uint8_t Bs[TILE * BK];   // 8 KB
    __shared__ float red[4];

    const int tid  = threadIdx.x;
    const int w    = tid >> 6;
    const int lane = tid & 63;

    // XCD-aware swizzle: blocks with id%8==x land on XCD x (round-robin
    // heuristic); give each XCD a 4-wide cb stripe so its B working set
    // (4 x 128KB) stays L2-resident. Perf-only; any mapping is correct.
    const int id  = blockIdx.y * gridDim.x + blockIdx.x;
    const int xcd = id & 7;
    const int j   = id >> 3;
    const int cb  = xcd * 4 + (j & 3);
    const int rb  = j >> 2;

    const uint8_t* gA = n1 + (size_t)rb * TILE * P_DIM;
    const uint8_t* gB = n2 + (size_t)cb * TILE * P_DIM;

    // waves 0,1 stage A (issues 0..3 / 4..7); waves 2,3 stage B
    const uint8_t* gbase = (w < 2) ? gA : gB;
    uint8_t* sbase = (w < 2) ? As : Bs;
    const int i0   = (w & 1) * 4;
    const int srow = lane >> 2;          // row within a 16-row issue
    const int scol = (lane & 3) * 16;    // byte col offset

    f32x4 acc[4][4];
    #pragma unroll
    for (int mi = 0; mi < 4; ++mi)
        #pragma unroll
        for (int ni = 0; ni < 4; ++ni)
            acc[mi][ni] = (f32x4){0.f, 0.f, 0.f, 0.f};

    const int wr = (w >> 1) * 64;
    const int wc = (w & 1) * 64;
    const int fr = lane & 15;
    const int q  = lane >> 4;

    for (int kt = 0; kt < P_DIM / BK; ++kt) {
        #pragma unroll
        for (int ii = 0; ii < 4; ++ii) {
            const int is = i0 + ii;
            const uint8_t* g =
                gbase + (size_t)(is * 16 + srow) * P_DIM + kt * BK + scol;
            __builtin_amdgcn_global_load_lds(
                (const __attribute__((address_space(1))) void*)g,
                (__attribute__((address_space(3))) void*)(sbase + is * 1024),
                16, 0, 0);
        }
        __syncthreads();

        lx2 af[4], bfr[4];
        #pragma unroll
        for (int i = 0; i < 4; ++i) {
            af[i]  = *(const lx2*)(As + (wr + i * 16 + fr) * BK + q * 16);
            bfr[i] = *(const lx2*)(Bs + (wc + i * 16 + fr) * BK + q * 16);
        }
        #pragma unroll
        for (int mi = 0; mi < 4; ++mi)
            #pragma unroll
            for (int ni = 0; ni < 4; ++ni) {
                acc[mi][ni] = __builtin_amdgcn_mfma_f32_16x16x32_fp8_fp8(
                    af[mi].x, bfr[ni].x, acc[mi][ni], 0, 0, 0);
                acc[mi][ni] = __builtin_amdgcn_mfma_f32_16x16x32_fp8_fp8(
                    af[mi].y, bfr[ni].y, acc[mi][ni], 0, 0, 0);
            }
        __syncthreads();
    }

    // Epilogue: acc = 256*cos -> sum (1 - acc/256)^2 over the tile.
    float local = 0.0f;
    #pragma unroll
    for (int mi = 0; mi < 4; ++mi)
        #pragma unroll
        for (int ni = 0; ni < 4; ++ni)
            #pragma unroll
            for (int r = 0; r < 4; ++r) {
                const float d = 1.0f - acc[mi][ni][r] * (1.0f / 256.0f);
                local += d * d;
            }
    #pragma unroll
    for (int off = 32; off > 0; off >>= 1) local += __shfl_down(local, off, 64);
    if (lane == 0) red[w] = local;
    __syncthreads();
    if (tid == 0) atomicAdd(loss_out, red[0] + red[1] + red[2] + red[3]);
}

extern "C" void kernel_launch(void* const* d_in, const int* in_sizes, int n_in,
                              void* d_out, int out_size, void* d_ws, size_t ws_size,
                              hipStream_t stream) {
    const float* in1 = (const float*)d_in[0];
    const float* in2 = (const float*)d_in[1];
    float* out = (float*)d_out;
    uint8_t* nrm = (uint8_t*)d_ws;                 // 8192x1024 fp8 = 8 MB

    norm_fp8_kernel<<<(U_ROWS * 2) / 4, 256, 0, stream>>>(in1, in2, nrm, out);

    dim3 grid(U_ROWS / TILE, U_ROWS / TILE);       // 32 x 32 = 1024 blocks
    cosloss_gemm_fp8<<<grid, 256, 0, stream>>>(
        nrm, nrm + (size_t)U_ROWS * P_DIM, out);
}

// Round 3
// 101.474 us; speedup vs baseline: 1.2516x; 1.0269x over previous
//
#include <hip/hip_runtime.h>
#include <hip/hip_bf16.h>
#include <stdint.h>

#define U_ROWS 4096
#define P_DIM  1024
#define TM     256     // A-tile rows per block
#define TN     128     // B-tile rows (C cols) per block
#define BK     64      // fp8 bytes per k-tile

typedef float f32x4 __attribute__((ext_vector_type(4)));
typedef long  lx2   __attribute__((ext_vector_type(2)));

// Row L2-normalize (eps-clamped), scale by 16, emit OCP fp8 e4m3 in a
// k-permuted layout: within each 64-col block, global k lives at
// pos = (k&7) + ((k>>3)&3)*16 + ((k>>5)&1)*8, so that a ds_read_b128 at
// byte q*16 yields k=q*8..q*8+7 (bytes 0-7) and k=32+q*8..32+q*8+7
// (bytes 8-15) -- exactly the two 16x16x32 fp8 MFMA fragments for quad q.
__global__ __launch_bounds__(256) void norm_fp8_kernel(
    const float* __restrict__ in1, const float* __restrict__ in2,
    uint8_t* __restrict__ out, float* __restrict__ loss_out) {
    const int w = threadIdx.x >> 6, lane = threadIdx.x & 63;
    const int row = blockIdx.x * 4 + w;
    const float* src = (row < U_ROWS) ? (in1 + (size_t)row * P_DIM)
                                      : (in2 + (size_t)(row - U_ROWS) * P_DIM);
    float4 v[4];
    float ss = 0.0f;
    #pragma unroll
    for (int j = 0; j < 4; ++j) {
        v[j] = ((const float4*)src)[j * 64 + lane];   // coalesced 16B/lane
        ss += v[j].x * v[j].x + v[j].y * v[j].y + v[j].z * v[j].z + v[j].w * v[j].w;
    }
    #pragma unroll
    for (int off = 32; off > 0; off >>= 1) ss += __shfl_xor(ss, off, 64);
    const float inv = 16.0f / fmaxf(sqrtf(ss), 1e-8f);

    uint8_t* orow = out + (size_t)row * P_DIM;
    #pragma unroll
    for (int j = 0; j < 4; ++j) {
        int c = j * 256 + lane * 4;                   // source col (mult of 4)
        int pos = (c & 4) + (((c >> 3) & 3) * 16) + (((c >> 5) & 1) * 8);
        int newc = (c & ~63) | pos;
        int d = __builtin_amdgcn_cvt_pk_fp8_f32(v[j].x * inv, v[j].y * inv, 0, false);
        d = __builtin_amdgcn_cvt_pk_fp8_f32(v[j].z * inv, v[j].w * inv, d, true);
        *(int*)(orow + newc) = d;
    }
    if (blockIdx.x == 0 && threadIdx.x == 0) *loss_out = 0.0f;
}

// C = N1*N2^T fused with sum((1-c)^2), fp8 e4m3 inputs scaled by 16
// (acc = 256*cos). 256x128 tile, 512 threads / 8 waves, each wave a 64x64
// sub-tile via 4x4 16x16x32 fp8 MFMA (two k-halves per b128 fragment).
// Staging: 24 KB/iter = 24 x 1KB global_load_lds issues, 3 per wave.
__global__ __launch_bounds__(512) void cosloss_gemm_fp8(
    const uint8_t* __restrict__ n1, const uint8_t* __restrict__ n2,
    float* __restrict__ loss_out) {
    __shared__ uint8_t As[TM * BK];   // 16 KB
    __shared__ uint8_t Bs[TN * BK];   // 8 KB
    __shared__ float red[8];

    const int tid  = threadIdx.x;
    const int w    = tid >> 6;        // 0..7
    const int lane = tid & 63;

    // XCD-aware swizzle (perf heuristic only): round-robin id%8 -> XCD;
    // each XCD keeps a 4-wide cb stripe (4 x 128 KB B rows) L2-resident.
    const int id  = blockIdx.x;       // 0..511
    const int xcd = id & 7;
    const int j   = id >> 3;          // 0..63
    const int cb  = xcd * 4 + (j & 3);  // 0..31
    const int rb  = j >> 2;             // 0..15

    const uint8_t* gA = n1 + (size_t)rb * TM * P_DIM;
    const uint8_t* gB = n2 + (size_t)cb * TN * P_DIM;

    // Staging: chunk c of 24; c<16 -> A chunk (16 rows x 64 B), else B.
    const int srow = lane >> 2;          // row within a 16-row chunk
    const int scol = (lane & 3) * 16;    // byte col offset
    const int chunk0 = w * 3;

    f32x4 acc[4][4];
    #pragma unroll
    for (int mi = 0; mi < 4; ++mi)
        #pragma unroll
        for (int ni = 0; ni < 4; ++ni)
            acc[mi][ni] = (f32x4){0.f, 0.f, 0.f, 0.f};

    const int wr = (w >> 1) * 64;     // wave row origin in 256
    const int wc = (w & 1) * 64;      // wave col origin in 128
    const int fr = lane & 15;
    const int q  = lane >> 4;

    for (int kt = 0; kt < P_DIM / BK; ++kt) {
        #pragma unroll
        for (int cc = 0; cc < 3; ++cc) {
            const int c = chunk0 + cc;            // wave-uniform
            const uint8_t* g;
            uint8_t* s;
            if (c < 16) {
                g = gA + (size_t)(c * 16 + srow) * P_DIM + kt * BK + scol;
                s = As + c * 1024;
            } else {
                g = gB + (size_t)((c - 16) * 16 + srow) * P_DIM + kt * BK + scol;
                s = Bs + (c - 16) * 1024;
            }
            __builtin_amdgcn_global_load_lds(
                (const __attribute__((address_space(1))) void*)g,
                (__attribute__((address_space(3))) void*)s,
                16, 0, 0);
        }
        __syncthreads();

        lx2 af[4], bfr[4];
        #pragma unroll
        for (int i = 0; i < 4; ++i) {
            af[i]  = *(const lx2*)(As + (wr + i * 16 + fr) * BK + q * 16);
            bfr[i] = *(const lx2*)(Bs + (wc + i * 16 + fr) * BK + q * 16);
        }
        #pragma unroll
        for (int mi = 0; mi < 4; ++mi)
            #pragma unroll
            for (int ni = 0; ni < 4; ++ni) {
                acc[mi][ni] = __builtin_amdgcn_mfma_f32_16x16x32_fp8_fp8(
                    af[mi].x, bfr[ni].x, acc[mi][ni], 0, 0, 0);
                acc[mi][ni] = __builtin_amdgcn_mfma_f32_16x16x32_fp8_fp8(
                    af[mi].y, bfr[ni].y, acc[mi][ni], 0, 0, 0);
            }
        __syncthreads();
    }

    // Epilogue: acc = 256*cos -> sum (1 - acc/256)^2 over the tile.
    float local = 0.0f;
    #pragma unroll
    for (int mi = 0; mi < 4; ++mi)
        #pragma unroll
        for (int ni = 0; ni < 4; ++ni)
            #pragma unroll
            for (int r = 0; r < 4; ++r) {
                const float d = 1.0f - acc[mi][ni][r] * (1.0f / 256.0f);
                local += d * d;
            }
    #pragma unroll
    for (int off = 32; off > 0; off >>= 1) local += __shfl_down(local, off, 64);
    if (lane == 0) red[w] = local;
    __syncthreads();
    if (tid == 0) {
        float t = 0.0f;
        #pragma unroll
        for (int i = 0; i < 8; ++i) t += red[i];
        atomicAdd(loss_out, t);
    }
}

extern "C" void kernel_launch(void* const* d_in, const int* in_sizes, int n_in,
                              void* d_out, int out_size, void* d_ws, size_t ws_size,
                              hipStream_t stream) {
    const float* in1 = (const float*)d_in[0];
    const float* in2 = (const float*)d_in[1];
    float* out = (float*)d_out;
    uint8_t* nrm = (uint8_t*)d_ws;                 // 8192x1024 fp8 = 8 MB

    norm_fp8_kernel<<<(U_ROWS * 2) / 4, 256, 0, stream>>>(in1, in2, nrm, out);

    cosloss_gemm_fp8<<<(U_ROWS / TM) * (U_ROWS / TN), 512, 0, stream>>>(
        nrm, nrm + (size_t)U_ROWS * P_DIM, out);
}